// Round 5
// baseline (46.154 us; speedup 1.0000x reference)
//
#include <hip/hip_runtime.h>

#define DIM 120
#define NB 8              // batches per block
#define RQ 4              // consecutive output rows per thread
#define BLOCK 256
#define ROWS_PER_BLOCK (BLOCK * RQ)   // 1024

// LDS layout: [d][b] with stride NB (8 dwords = 32 B, b128-aligned).
// Swizzle: d -> d ^ ((d>>2)&3)  (involution, bijective within each 4-group)
// spreads step-4 index ladders across 4 b128 bank-slots.
__device__ __host__ __forceinline__ int swzoff(int idx) {
    return (idx ^ ((idx >> 2) & 3)) << 5;   // BYTE offset of row idx
}

// ---- Fused preprocess: CSR row pointers + packed entries with
//      pre-swizzled LDS byte offsets: {off1 | off2<<16, palette_bits} ----
__global__ void pre_kernel(const int* __restrict__ out_idx, int K, int H,
                           int* __restrict__ row_start,
                           const int* __restrict__ i1, const int* __restrict__ i2,
                           const int* __restrict__ cb, const float* __restrict__ pal,
                           uint2* __restrict__ ent) {
    int t = blockIdx.x * blockDim.x + threadIdx.x;
    if (t <= H) {
        int lo = 0, hi = K;
        while (lo < hi) {
            int mid = (lo + hi) >> 1;
            if (out_idx[mid] < t) lo = mid + 1; else hi = mid;
        }
        row_start[t] = lo;
    }
    if (t < K) {
        uint2 e;
        e.x = (unsigned)swzoff(i1[t]) | ((unsigned)swzoff(i2[t]) << 16);
        e.y = __float_as_uint(pal[cb[t]]);
        ent[t] = e;
    }
}

// ---- Main: thread = RQ consecutive rows x NB batches ----
__global__ __launch_bounds__(BLOCK) void tp_kernel(
    const float* __restrict__ in1, const float* __restrict__ in2,
    const uint2* __restrict__ ent, const int* __restrict__ row_start,
    float* __restrict__ out, int H) {
    __shared__ __align__(16) float s1t[DIM * NB];
    __shared__ __align__(16) float s2t[DIM * NB];

    const int b0 = blockIdx.y * NB;
    // Stage NB batch-rows, transposed to [d][b], swizzled. 2*DIM*(NB/4)=480 cells.
    for (int t = threadIdx.x; t < 2 * DIM * (NB / 4); t += BLOCK) {
        const int arr = (t >= DIM * (NB / 4));
        const int c = arr ? t - DIM * (NB / 4) : t;
        const int d = c >> 1;          // 0..119
        const int bg = c & 1;          // float4 group along b
        const float* __restrict__ src = arr ? in2 : in1;
        const size_t base = (size_t)(b0 + 4 * bg) * DIM + d;
        float4 v;
        v.x = src[base + 0 * DIM];
        v.y = src[base + 1 * DIM];
        v.z = src[base + 2 * DIM];
        v.w = src[base + 3 * DIM];
        char* dst = (char*)(arr ? s2t : s1t);
        *(float4*)(dst + swzoff(d) + 16 * bg) = v;
    }
    __syncthreads();

    const int o0 = blockIdx.x * ROWS_PER_BLOCK + (int)threadIdx.x * RQ;
    if (o0 >= H) return;

    int rs[RQ + 1];
    *(int4*)rs = *(const int4*)(row_start + o0);   // o0 % 4 == 0 -> aligned
    rs[RQ] = row_start[o0 + RQ];

    float acc[RQ][NB];
#pragma unroll
    for (int r = 0; r < RQ; ++r)
#pragma unroll
        for (int b = 0; b < NB; ++b) acc[r][b] = 0.0f;

#pragma unroll
    for (int r = 0; r < RQ; ++r) {
        for (int k = rs[r]; k < rs[r + 1]; ++k) {
            const uint2 e = ent[k];
            const char* p1 = (const char*)s1t + (e.x & 0xffffu);
            const char* p2 = (const char*)s2t + (e.x >> 16);
            const float4 x0 = *(const float4*)(p1);
            const float4 x1 = *(const float4*)(p1 + 16);
            const float4 y0 = *(const float4*)(p2);
            const float4 y1 = *(const float4*)(p2 + 16);
            const float v = __uint_as_float(e.y);
            acc[r][0] = fmaf(v * x0.x, y0.x, acc[r][0]);
            acc[r][1] = fmaf(v * x0.y, y0.y, acc[r][1]);
            acc[r][2] = fmaf(v * x0.z, y0.z, acc[r][2]);
            acc[r][3] = fmaf(v * x0.w, y0.w, acc[r][3]);
            acc[r][4] = fmaf(v * x1.x, y1.x, acc[r][4]);
            acc[r][5] = fmaf(v * x1.y, y1.y, acc[r][5]);
            acc[r][6] = fmaf(v * x1.z, y1.z, acc[r][6]);
            acc[r][7] = fmaf(v * x1.w, y1.w, acc[r][7]);
        }
    }

    // Stores: per batch, 4 consecutive rows -> one dwordx4.
#pragma unroll
    for (int b = 0; b < NB; ++b) {
        float4 o4 = make_float4(acc[0][b], acc[1][b], acc[2][b], acc[3][b]);
        *(float4*)(out + (size_t)(b0 + b) * H + o0) = o4;
    }
}

extern "C" void kernel_launch(void* const* d_in, const int* in_sizes, int n_in,
                              void* d_out, int out_size, void* d_ws, size_t ws_size,
                              hipStream_t stream) {
    const float* in1 = (const float*)d_in[0];
    const float* in2 = (const float*)d_in[1];
    const float* pal = (const float*)d_in[2];
    const int*   i1  = (const int*)d_in[3];
    const int*   i2  = (const int*)d_in[4];
    const int*   oi  = (const int*)d_in[5];
    const int*   cb  = (const int*)d_in[6];

    const int K = in_sizes[3];
    const int B = in_sizes[0] / DIM;   // 2048
    const int H = out_size / B;        // 14400

    uint2* ent = (uint2*)d_ws;
    int* row_start = (int*)((char*)d_ws + (size_t)K * sizeof(uint2));

    {
        const int n = (K > H + 1) ? K : (H + 1);
        pre_kernel<<<(n + 255) / 256, 256, 0, stream>>>(oi, K, H, row_start,
                                                        i1, i2, cb, pal, ent);
    }

    dim3 grid((H + ROWS_PER_BLOCK - 1) / ROWS_PER_BLOCK, B / NB);
    tp_kernel<<<grid, BLOCK, 0, stream>>>(in1, in2, ent, row_start,
                                          (float*)d_out, H);
}

// Round 6
// 45.932 us; speedup vs baseline: 1.0048x; 1.0048x over previous
//
#include <hip/hip_runtime.h>

#define DIM 120
#define NB 8              // batches per block
#define NBP 12            // LDS row stride in dwords (48 B): 8 distinct b128 bank phases
#define RQ 4              // consecutive output rows per thread
#define BLOCK 256
#define ROWS_PER_BLOCK (BLOCK * RQ)   // 1024

// byte offset of row idx in the [d][b] transposed LDS tile
__device__ __forceinline__ unsigned rowoff(int idx) { return (unsigned)idx * (NBP * 4); }

// ---- Fused preprocess: CSR row pointers + packed entries with
//      pre-computed LDS byte offsets: {off1 | off2<<16, palette_bits} ----
__global__ void pre_kernel(const int* __restrict__ out_idx, int K, int H,
                           int* __restrict__ row_start,
                           const int* __restrict__ i1, const int* __restrict__ i2,
                           const int* __restrict__ cb, const float* __restrict__ pal,
                           uint2* __restrict__ ent) {
    int t = blockIdx.x * blockDim.x + threadIdx.x;
    if (t <= H) {
        int lo = 0, hi = K;
        while (lo < hi) {
            int mid = (lo + hi) >> 1;
            if (out_idx[mid] < t) lo = mid + 1; else hi = mid;
        }
        row_start[t] = lo;
    }
    if (t < K) {
        uint2 e;
        e.x = (unsigned)(i1[t] * (NBP * 4)) | ((unsigned)(i2[t] * (NBP * 4)) << 16);
        e.y = __float_as_uint(pal[cb[t]]);
        ent[t] = e;
    }
}

// ---- Main: thread = RQ consecutive rows x NB batches; wave stores 1KB bursts ----
__global__ __launch_bounds__(BLOCK) void tp_kernel(
    const float* __restrict__ in1, const float* __restrict__ in2,
    const uint2* __restrict__ ent, const int* __restrict__ row_start,
    float* __restrict__ out, int H) {
    __shared__ __align__(16) float s1t[DIM * NBP];
    __shared__ __align__(16) float s2t[DIM * NBP];

    const int b0 = blockIdx.y * NB;
    // Stage NB batch-rows transposed to [d][b]: cell=(d,bg): 4 strided global
    // scalar loads + one ds_write_b128 at dword offset d*12+4*bg.
    for (int t = threadIdx.x; t < 2 * DIM * (NB / 4); t += BLOCK) {
        const int arr = (t >= DIM * (NB / 4));
        const int c = arr ? t - DIM * (NB / 4) : t;
        const int d = c >> 1;          // 0..119
        const int bg = c & 1;          // float4 group along b
        const float* __restrict__ src = arr ? in2 : in1;
        const size_t base = (size_t)(b0 + 4 * bg) * DIM + d;
        float4 v;
        v.x = src[base + 0 * DIM];
        v.y = src[base + 1 * DIM];
        v.z = src[base + 2 * DIM];
        v.w = src[base + 3 * DIM];
        float* dst = arr ? s2t : s1t;
        *(float4*)(dst + d * NBP + 4 * bg) = v;
    }
    __syncthreads();

    const int o0 = blockIdx.x * ROWS_PER_BLOCK + (int)threadIdx.x * RQ;
    if (o0 >= H) return;

    int rs[RQ + 1];
    *(int4*)rs = *(const int4*)(row_start + o0);   // o0 % 4 == 0 -> 16B aligned
    rs[RQ] = row_start[o0 + RQ];

    float acc[RQ][NB];
#pragma unroll
    for (int r = 0; r < RQ; ++r)
#pragma unroll
        for (int b = 0; b < NB; ++b) acc[r][b] = 0.0f;

#pragma unroll
    for (int r = 0; r < RQ; ++r) {
        for (int k = rs[r]; k < rs[r + 1]; ++k) {
            const uint2 e = ent[k];
            const char* p1 = (const char*)s1t + (e.x & 0xffffu);
            const char* p2 = (const char*)s2t + (e.x >> 16);
            const float4 x0 = *(const float4*)(p1);
            const float4 x1 = *(const float4*)(p1 + 16);
            const float4 y0 = *(const float4*)(p2);
            const float4 y1 = *(const float4*)(p2 + 16);
            const float v = __uint_as_float(e.y);
            acc[r][0] = fmaf(v * x0.x, y0.x, acc[r][0]);
            acc[r][1] = fmaf(v * x0.y, y0.y, acc[r][1]);
            acc[r][2] = fmaf(v * x0.z, y0.z, acc[r][2]);
            acc[r][3] = fmaf(v * x0.w, y0.w, acc[r][3]);
            acc[r][4] = fmaf(v * x1.x, y1.x, acc[r][4]);
            acc[r][5] = fmaf(v * x1.y, y1.y, acc[r][5]);
            acc[r][6] = fmaf(v * x1.z, y1.z, acc[r][6]);
            acc[r][7] = fmaf(v * x1.w, y1.w, acc[r][7]);
        }
    }

    // Stores: per batch, 4 consecutive rows -> one dwordx4; wave = 1KB burst.
#pragma unroll
    for (int b = 0; b < NB; ++b) {
        float4 o4 = make_float4(acc[0][b], acc[1][b], acc[2][b], acc[3][b]);
        *(float4*)(out + (size_t)(b0 + b) * H + o0) = o4;
    }
}

extern "C" void kernel_launch(void* const* d_in, const int* in_sizes, int n_in,
                              void* d_out, int out_size, void* d_ws, size_t ws_size,
                              hipStream_t stream) {
    const float* in1 = (const float*)d_in[0];
    const float* in2 = (const float*)d_in[1];
    const float* pal = (const float*)d_in[2];
    const int*   i1  = (const int*)d_in[3];
    const int*   i2  = (const int*)d_in[4];
    const int*   oi  = (const int*)d_in[5];
    const int*   cb  = (const int*)d_in[6];

    const int K = in_sizes[3];
    const int B = in_sizes[0] / DIM;   // 2048
    const int H = out_size / B;        // 14400

    uint2* ent = (uint2*)d_ws;
    int* row_start = (int*)((char*)d_ws + (size_t)K * sizeof(uint2));

    {
        const int n = (K > H + 1) ? K : (H + 1);
        pre_kernel<<<(n + 255) / 256, 256, 0, stream>>>(oi, K, H, row_start,
                                                        i1, i2, cb, pal, ent);
    }

    dim3 grid((H + ROWS_PER_BLOCK - 1) / ROWS_PER_BLOCK, B / NB);
    tp_kernel<<<grid, BLOCK, 0, stream>>>(in1, in2, ent, row_start,
                                          (float*)d_out, H);
}

// Round 7
// 39.928 us; speedup vs baseline: 1.1559x; 1.1504x over previous
//
#include <hip/hip_runtime.h>

#define DIM 120
#define NB 16            // batch rows per block
#define NBP 20           // padded LDS stride in dwords (multiple of 4 -> b128-aligned)
#define BLOCK 256        // one thread per output row
#define NG (NB / 4)      // float4 groups along b

// ---- Fused preprocess: CSR row pointers + packed {i1,i2,palette} entries ----
__global__ void pre_kernel(const int* __restrict__ out_idx, int K, int H,
                           int* __restrict__ row_start,
                           const int* __restrict__ i1, const int* __restrict__ i2,
                           const int* __restrict__ cb, const float* __restrict__ pal,
                           uint2* __restrict__ ent) {
    int t = blockIdx.x * blockDim.x + threadIdx.x;
    if (t <= H) {
        int lo = 0, hi = K;
        while (lo < hi) {
            int mid = (lo + hi) >> 1;
            if (out_idx[mid] < t) lo = mid + 1; else hi = mid;
        }
        row_start[t] = lo;
    }
    if (t < K) {
        uint2 e;
        e.x = (unsigned)i1[t] | ((unsigned)i2[t] << 16);
        e.y = __float_as_uint(pal[cb[t]]);
        ent[t] = e;
    }
}

// ---- Main: thread = one output row o x NB batch rows.
// Entry loads software-pipelined: first entry issued BEFORE staging (latency
// hides under stage+barrier); ent[k+1] prefetched while processing entry k.
__global__ __launch_bounds__(BLOCK, 8) void tp_kernel(
    const float* __restrict__ in1, const float* __restrict__ in2,
    const uint2* __restrict__ ent, const int* __restrict__ row_start,
    float* __restrict__ out, int H) {
    __shared__ __align__(16) float s1t[DIM * NBP];
    __shared__ __align__(16) float s2t[DIM * NBP];

    // --- issue per-row metadata loads first: latency overlaps staging ---
    const int o = blockIdx.x * BLOCK + threadIdx.x;
    const bool act = (o < H);
    const int k0 = act ? row_start[o] : 0;
    const int k1 = act ? row_start[o + 1] : 0;
    uint2 e = (k0 < k1) ? ent[k0] : make_uint2(0u, 0u);

    // --- stage NB batch-rows transposed to [d][b] ---
    const int b0 = blockIdx.y * NB;
    for (int t = threadIdx.x; t < 2 * DIM * NG; t += BLOCK) {
        const int arr = (t >= DIM * NG);
        const int c = arr ? t - DIM * NG : t;
        const int d = c % DIM;
        const int g = c / DIM;
        const float* __restrict__ src = arr ? in2 : in1;
        const size_t base = (size_t)(b0 + 4 * g) * DIM + d;
        float4 v;
        v.x = src[base + 0 * DIM];
        v.y = src[base + 1 * DIM];
        v.z = src[base + 2 * DIM];
        v.w = src[base + 3 * DIM];
        float* dst = arr ? s2t : s1t;
        *(float4*)(dst + d * NBP + 4 * g) = v;
    }
    __syncthreads();

    if (!act) return;

    float acc[NB];
#pragma unroll
    for (int b = 0; b < NB; ++b) acc[b] = 0.0f;

    for (int k = k0; k < k1; ++k) {
        // prefetch next entry before touching LDS for this one
        const uint2 en = (k + 1 < k1) ? ent[k + 1] : e;
        const float4* __restrict__ pa = (const float4*)(s1t + (e.x & 0xffffu) * NBP);
        const float4* __restrict__ pc = (const float4*)(s2t + (e.x >> 16) * NBP);
        const float v = __uint_as_float(e.y);
#pragma unroll
        for (int j = 0; j < NG; ++j) {
            const float4 x = pa[j];
            const float4 y = pc[j];
            acc[4 * j + 0] = fmaf(v * x.x, y.x, acc[4 * j + 0]);
            acc[4 * j + 1] = fmaf(v * x.y, y.y, acc[4 * j + 1]);
            acc[4 * j + 2] = fmaf(v * x.z, y.z, acc[4 * j + 2]);
            acc[4 * j + 3] = fmaf(v * x.w, y.w, acc[4 * j + 3]);
        }
        e = en;
    }

#pragma unroll
    for (int b = 0; b < NB; ++b)
        out[(size_t)(b0 + b) * H + o] = acc[b];
}

extern "C" void kernel_launch(void* const* d_in, const int* in_sizes, int n_in,
                              void* d_out, int out_size, void* d_ws, size_t ws_size,
                              hipStream_t stream) {
    const float* in1 = (const float*)d_in[0];
    const float* in2 = (const float*)d_in[1];
    const float* pal = (const float*)d_in[2];
    const int*   i1  = (const int*)d_in[3];
    const int*   i2  = (const int*)d_in[4];
    const int*   oi  = (const int*)d_in[5];
    const int*   cb  = (const int*)d_in[6];

    const int K = in_sizes[3];
    const int B = in_sizes[0] / DIM;   // 2048
    const int H = out_size / B;        // 14400

    uint2* ent = (uint2*)d_ws;
    int* row_start = (int*)((char*)d_ws + (size_t)K * sizeof(uint2));

    {
        const int n = (K > H + 1) ? K : (H + 1);
        pre_kernel<<<(n + 255) / 256, 256, 0, stream>>>(oi, K, H, row_start,
                                                        i1, i2, cb, pal, ent);
    }

    dim3 grid((H + BLOCK - 1) / BLOCK, B / NB);
    tp_kernel<<<grid, BLOCK, 0, stream>>>(in1, in2, ent, row_start,
                                          (float*)d_out, H);
}

// Round 8
// 33.315 us; speedup vs baseline: 1.3854x; 1.1985x over previous
//
#include <hip/hip_runtime.h>

#define DIM 120
#define NB 16            // batch rows per block
#define NBP 20           // padded LDS stride in dwords (multiple of 4 -> b128-aligned)
#define BLOCK 256        // one thread per output row
#define NG (NB / 4)      // float4 groups along b
#define NXCD 8

// ---- Fused preprocess: CSR row pointers + packed {i1,i2,palette} entries ----
__global__ void pre_kernel(const int* __restrict__ out_idx, int K, int H,
                           int* __restrict__ row_start,
                           const int* __restrict__ i1, const int* __restrict__ i2,
                           const int* __restrict__ cb, const float* __restrict__ pal,
                           uint2* __restrict__ ent) {
    int t = blockIdx.x * blockDim.x + threadIdx.x;
    if (t <= H) {
        int lo = 0, hi = K;
        while (lo < hi) {
            int mid = (lo + hi) >> 1;
            if (out_idx[mid] < t) lo = mid + 1; else hi = mid;
        }
        row_start[t] = lo;
    }
    if (t < K) {
        uint2 e;
        e.x = (unsigned)i1[t] | ((unsigned)i2[t] << 16);
        e.y = __float_as_uint(pal[cb[t]]);
        ent[t] = e;
    }
}

// ---- Main: thread = one output row o x NB batch rows (R4 structure) ----
// blockIdx.x remapped with a bijective XCD-chunked swizzle so each XCD owns a
// CONTIGUOUS o-range per b-row -> L2 writeback streams are contiguous.
__global__ __launch_bounds__(BLOCK, 8) void tp_kernel(
    const float* __restrict__ in1, const float* __restrict__ in2,
    const uint2* __restrict__ ent, const int* __restrict__ row_start,
    float* __restrict__ out, int H, int nbx) {
    // bijective chunked swizzle over the o-block dimension (m204 form):
    // dispatch round-robins linear id over XCDs; give XCD its chunk.
    int x = blockIdx.x;
    {
        const int q = nbx / NXCD, r = nbx % NXCD;
        const int xcd = x % NXCD, pos = x / NXCD;
        x = (xcd < r) ? (xcd * (q + 1) + pos) : (r * (q + 1) + (xcd - r) * q + pos);
    }

    __shared__ __align__(16) float s1t[DIM * NBP];
    __shared__ __align__(16) float s2t[DIM * NBP];

    const int b0 = blockIdx.y * NB;
    for (int t = threadIdx.x; t < 2 * DIM * NG; t += BLOCK) {
        const int arr = (t >= DIM * NG);
        const int c = arr ? t - DIM * NG : t;
        const int d = c % DIM;
        const int g = c / DIM;
        const float* __restrict__ src = arr ? in2 : in1;
        const size_t base = (size_t)(b0 + 4 * g) * DIM + d;
        float4 v;
        v.x = src[base + 0 * DIM];
        v.y = src[base + 1 * DIM];
        v.z = src[base + 2 * DIM];
        v.w = src[base + 3 * DIM];
        float* dst = arr ? s2t : s1t;
        *(float4*)(dst + d * NBP + 4 * g) = v;
    }
    __syncthreads();

    const int o = x * BLOCK + threadIdx.x;
    if (o >= H) return;
    const int k0 = row_start[o];
    const int k1 = row_start[o + 1];

    float acc[NB];
#pragma unroll
    for (int b = 0; b < NB; ++b) acc[b] = 0.0f;

    for (int k = k0; k < k1; ++k) {
        const uint2 e = ent[k];
        const float4* __restrict__ pa = (const float4*)(s1t + (e.x & 0xffffu) * NBP);
        const float4* __restrict__ pc = (const float4*)(s2t + (e.x >> 16) * NBP);
        const float v = __uint_as_float(e.y);
#pragma unroll
        for (int j = 0; j < NG; ++j) {
            const float4 x4 = pa[j];
            const float4 y4 = pc[j];
            acc[4 * j + 0] = fmaf(v * x4.x, y4.x, acc[4 * j + 0]);
            acc[4 * j + 1] = fmaf(v * x4.y, y4.y, acc[4 * j + 1]);
            acc[4 * j + 2] = fmaf(v * x4.z, y4.z, acc[4 * j + 2]);
            acc[4 * j + 3] = fmaf(v * x4.w, y4.w, acc[4 * j + 3]);
        }
    }

#pragma unroll
    for (int b = 0; b < NB; ++b)
        out[(size_t)(b0 + b) * H + o] = acc[b];
}

extern "C" void kernel_launch(void* const* d_in, const int* in_sizes, int n_in,
                              void* d_out, int out_size, void* d_ws, size_t ws_size,
                              hipStream_t stream) {
    const float* in1 = (const float*)d_in[0];
    const float* in2 = (const float*)d_in[1];
    const float* pal = (const float*)d_in[2];
    const int*   i1  = (const int*)d_in[3];
    const int*   i2  = (const int*)d_in[4];
    const int*   oi  = (const int*)d_in[5];
    const int*   cb  = (const int*)d_in[6];

    const int K = in_sizes[3];
    const int B = in_sizes[0] / DIM;   // 2048
    const int H = out_size / B;        // 14400

    uint2* ent = (uint2*)d_ws;
    int* row_start = (int*)((char*)d_ws + (size_t)K * sizeof(uint2));

    {
        const int n = (K > H + 1) ? K : (H + 1);
        pre_kernel<<<(n + 255) / 256, 256, 0, stream>>>(oi, K, H, row_start,
                                                        i1, i2, cb, pal, ent);
    }

    const int nbx = (H + BLOCK - 1) / BLOCK;   // 57
    dim3 grid(nbx, B / NB);
    tp_kernel<<<grid, BLOCK, 0, stream>>>(in1, in2, ent, row_start,
                                          (float*)d_out, H, nbx);
}